// Round 13
// baseline (414.204 us; speedup 1.0000x reference)
//
#include <hip/hip_runtime.h>
#include <math.h>

#define BB     1024
#define CC     256
#define HWN    361
#define SEH    64
#define P3C    768
#define SLICE  (CC * HWN)      // 92416 floats per batch row
#define SLICE4 (SLICE / 4)     // 23104 f32x4 = 22*1024 + 576
#define NW     16
#define FULLJ  22
#define TAILN  576

typedef float    f32x4 __attribute__((ext_vector_type(4)));
typedef _Float16 f16x2 __attribute__((ext_vector_type(2)));

__device__ __forceinline__ unsigned pack2(float a, float b) {
    f16x2 h; h[0] = (_Float16)a; h[1] = (_Float16)b;
    return __builtin_bit_cast(unsigned, h);
}
// order-preserving float->uint map (for atomicMax on floats incl. negatives)
__device__ __forceinline__ unsigned fmap(float f) {
    unsigned b = __builtin_bit_cast(unsigned, f);
    return (b & 0x80000000u) ? ~b : (b | 0x80000000u);
}
__device__ __forceinline__ float funmap(unsigned u) {
    unsigned b = (u & 0x80000000u) ? (u ^ 0x80000000u) : ~u;
    return __builtin_bit_cast(float, b);
}

// One block (16 waves) per batch row b. Fully flat f32x4 streaming:
// pool = dwordx4 loads + LDS atomic sum/max + f16-pack pinned in VGPRs;
// MLP in LDS; apply = unpack + FMA + NT dwordx4 stores. x read exactly once,
// never re-read from any cache level; all HBM traffic is wide.
__global__ __launch_bounds__(1024, 4) void k_se_fused(
        const float* __restrict__ x,
        const float* __restrict__ mask,
        const float* __restrict__ msum,
        const float* __restrict__ msqrt,
        const float* __restrict__ w1,
        const float* __restrict__ b1,
        const float* __restrict__ w2,
        const float* __restrict__ b2,
        float* __restrict__ out) {
    __shared__ float    m_s[HWN];
    __shared__ float    sum_s[CC];
    __shared__ unsigned max_s[CC];
    __shared__ float    p_s[P3C];
    __shared__ float    part_s[NW * SEH];
    __shared__ float    hid_s[SEH];
    __shared__ float    g_s[CC];
    __shared__ float    be_s[CC];

    const int tid = threadIdx.x;
    const int b   = blockIdx.x;

    if (tid < HWN) m_s[tid] = mask[(size_t)b * HWN + tid];
    if (tid < CC) { sum_s[tid] = 0.0f; max_s[tid] = 0x007FFFFFu; } // fmap(-inf)
    __syncthreads();

    const float inv_div = 1.0f / msum[b];
    const float bscale  = (msqrt[b] - 14.0f) * 0.1f;   // (sqrt(div)-B_AVG)/10

    const f32x4* x4 = (const f32x4*)(x + (size_t)b * SLICE);
    unsigned pk[FULLJ + 1][2];          // packed f16 payload, static indices

    // ---- pool: one f32x4 per iteration ----
    auto pool_quad = [&](int i, unsigned* pkj) {
        f32x4 v = x4[i];
        const unsigned e0 = (unsigned)i * 4u;
        const unsigned c0 = e0 / 361u;
        const unsigned c3 = (e0 + 3u) / 361u;
        float cand[4];
        #pragma unroll
        for (int q = 0; q < 4; ++q) {
            unsigned e  = e0 + q;
            unsigned c  = e / 361u;
            unsigned hw = e - c * 361u;
            cand[q] = fmaf(1.0f - m_s[hw], -5000.0f, v[q]);
        }
        if (c0 == c3) {
            float s  = (v[0] + v[1]) + (v[2] + v[3]);
            float mx = fmaxf(fmaxf(cand[0], cand[1]), fmaxf(cand[2], cand[3]));
            atomicAdd(&sum_s[c0], s);
            atomicMax(&max_s[c0], fmap(mx));
        } else {
            const int ks = (int)(361u * c3 - e0);   // first elem in channel c3
            float slo = 0.0f, shi = 0.0f, mlo = -INFINITY, mhi = -INFINITY;
            #pragma unroll
            for (int q = 0; q < 4; ++q) {
                if (q < ks) { slo += v[q]; mlo = fmaxf(mlo, cand[q]); }
                else        { shi += v[q]; mhi = fmaxf(mhi, cand[q]); }
            }
            atomicAdd(&sum_s[c0], slo);  atomicMax(&max_s[c0], fmap(mlo));
            atomicAdd(&sum_s[c3], shi);  atomicMax(&max_s[c3], fmap(mhi));
        }
        pkj[0] = pack2(v[0], v[1]);
        pkj[1] = pack2(v[2], v[3]);
        asm volatile("" : "+v"(pkj[0]), "+v"(pkj[1]));   // pin: no DCE/remat
    };

    #pragma unroll
    for (int j = 0; j < FULLJ; ++j) pool_quad(tid + j * 1024, pk[j]);
    if (tid < TAILN)                pool_quad(tid + FULLJ * 1024, pk[FULLJ]);
    __syncthreads();

    // ---- pooled vector ----
    if (tid < CC) {
        float mean = sum_s[tid] * inv_div;
        p_s[tid]        = mean;
        p_s[256 + tid]  = mean * bscale;
        p_s[512 + tid]  = funmap(max_s[tid]);
    }
    __syncthreads();

    // ---- layer 1 (768 -> 64): 16 partials (48 long) per output ----
    {
        const int q = tid >> 6, s = tid & 63;
        const float* w1r = w1  + s * P3C + q * 48;
        const float* pp  = p_s + q * 48;
        float acc = 0.0f;
        #pragma unroll 8
        for (int j = 0; j < 48; ++j) acc = fmaf(pp[j], w1r[j], acc);
        part_s[q * SEH + s] = acc;
    }
    __syncthreads();
    if (tid < SEH) {
        float h = b1[tid];
        #pragma unroll
        for (int q = 0; q < NW; ++q) h += part_s[q * SEH + tid];
        hid_s[tid] = fmaxf(h, 0.0f);
    }
    __syncthreads();

    // ---- layer 2 (64 -> 512) ----
    if (tid < 512) {
        float a = b2[tid];
        const float* w2r = w2 + (size_t)tid * SEH;
        #pragma unroll 8
        for (int ss = 0; ss < SEH; ++ss) a = fmaf(hid_s[ss], w2r[ss], a);
        if (tid < 256) g_s[tid]        = 1.0f / (1.0f + __expf(-a));
        else           be_s[tid - 256] = a;
    }
    __syncthreads();

    // ---- apply from pinned registers; NT dwordx4 stores; zero reads ----
    f32x4* o4 = (f32x4*)(out + (size_t)b * SLICE);
    auto apply_quad = [&](int i, const unsigned* pkj) {
        const f16x2 h0 = __builtin_bit_cast(f16x2, pkj[0]);
        const f16x2 h1 = __builtin_bit_cast(f16x2, pkj[1]);
        const float vv[4] = {(float)h0[0], (float)h0[1],
                             (float)h1[0], (float)h1[1]};
        const unsigned e0 = (unsigned)i * 4u;
        f32x4 r;
        #pragma unroll
        for (int q = 0; q < 4; ++q) {
            unsigned e  = e0 + q;
            unsigned c  = e / 361u;
            unsigned hw = e - c * 361u;
            r[q] = fmaf(g_s[c], vv[q], be_s[c]) * m_s[hw];
        }
        __builtin_nontemporal_store(r, &o4[i]);
    };

    #pragma unroll
    for (int j = 0; j < FULLJ; ++j) apply_quad(tid + j * 1024, pk[j]);
    if (tid < TAILN)                apply_quad(tid + FULLJ * 1024, pk[FULLJ]);
}

extern "C" void kernel_launch(void* const* d_in, const int* in_sizes, int n_in,
                              void* d_out, int out_size, void* d_ws, size_t ws_size,
                              hipStream_t stream) {
    const float* x     = (const float*)d_in[0];
    const float* mask  = (const float*)d_in[1];
    const float* msum  = (const float*)d_in[2];
    const float* msqrt = (const float*)d_in[3];
    const float* w1    = (const float*)d_in[4];
    const float* b1    = (const float*)d_in[5];
    const float* w2    = (const float*)d_in[6];
    const float* b2    = (const float*)d_in[7];
    float* out = (float*)d_out;

    k_se_fused<<<BB, 1024, 0, stream>>>(x, mask, msum, msqrt, w1, b1, w2, b2, out);
}

// Round 14
// 222.368 us; speedup vs baseline: 1.8627x; 1.8627x over previous
//
#include <hip/hip_runtime.h>
#include <math.h>

#define BB     1024
#define CC     256
#define HWN    361
#define SEH    64
#define P3C    768
#define SLICE  (CC * HWN)      // 92416 floats per batch row
#define NW     16
#define GQ     361             // f32x4 quads per 4-channel group (1444 floats)

typedef float    f32x4 __attribute__((ext_vector_type(4)));
typedef _Float16 f16x2 __attribute__((ext_vector_type(2)));

__device__ __forceinline__ unsigned pack2(float a, float b) {
    f16x2 h; h[0] = (_Float16)a; h[1] = (_Float16)b;
    return __builtin_bit_cast(unsigned, h);
}

// One block (16 waves) per batch row b. Wave wv owns 4-channel groups
// 4wv..4wv+3. Pool: f32x4 loads, per-quad channel split (magic-div),
// select-accumulate into 4 per-lane accumulators, butterfly reduce.
// Payload packed to f16 pairs pinned in regs (direct constant indexing
// only -- R13's pointer-into-lambda caused scratch spills). Apply:
// unpack + select + NT f32x4 stores. x is read exactly once.
__global__ __launch_bounds__(1024, 4) void k_se_fused(
        const float* __restrict__ x,
        const float* __restrict__ mask,
        const float* __restrict__ msum,
        const float* __restrict__ msqrt,
        const float* __restrict__ w1,
        const float* __restrict__ b1,
        const float* __restrict__ w2,
        const float* __restrict__ b2,
        float* __restrict__ out) {
    __shared__ float m_s[HWN];
    __shared__ float pen_s[HWN];
    __shared__ float p_s[P3C];
    __shared__ float part_s[NW * SEH];
    __shared__ float hid_s[SEH];
    __shared__ float g_s[CC];
    __shared__ float be_s[CC];

    const int tid  = threadIdx.x;
    const int lane = tid & 63;
    const int wv   = tid >> 6;          // 0..15
    const int b    = blockIdx.x;

    if (tid < HWN) {
        float m = mask[(size_t)b * HWN + tid];
        m_s[tid]   = m;
        pen_s[tid] = (1.0f - m) * -5000.0f;
    }
    __syncthreads();

    const float inv_div = 1.0f / msum[b];
    const float bscale  = (msqrt[b] - 14.0f) * 0.1f;   // (sqrt(div)-B_AVG)/10

    const f32x4* x4 = (const f32x4*)(x + (size_t)b * SLICE);
    const float NINF = -__builtin_inff();

    unsigned pk[4][6][2];               // pinned payload; constant indices ONLY

    // ================= pool =================
    #pragma unroll
    for (int g = 0; g < 4; ++g) {
        const int gidx  = 4 * wv + g;   // group id 0..63
        const int qbase = gidx * GQ;
        float sc[4] = {0.0f, 0.0f, 0.0f, 0.0f};
        float mc[4] = {NINF, NINF, NINF, NINF};

        #pragma unroll
        for (int j = 0; j < 6; ++j) {
            if (j == 5 && lane >= 41) continue;      // 361 = 5*64 + 41
            const int      qi  = lane + 64 * j;      // quad within group
            const f32x4    v   = x4[qbase + qi];
            const unsigned e0  = 4u * (unsigned)qi;  // elem within group
            const unsigned cA  = e0 / 361u;
            const unsigned cB  = (e0 + 3u) / 361u;   // cA or cA+1
            const unsigned bnd  = cB * 361u;         // e >= bnd -> channel cB
            const unsigned bndA = cA * 361u;

            float pre = 0.0f, post = 0.0f, mpre = NINF, mpost = NINF;
            #pragma unroll
            for (int q = 0; q < 4; ++q) {
                const unsigned e   = e0 + q;
                const bool     inB = (e >= bnd);
                const unsigned hw  = e - (inB ? bnd : bndA);
                const float cand   = v[q] + pen_s[hw];
                pre   += inB ? 0.0f : v[q];
                post  += inB ? v[q] : 0.0f;
                mpre   = fmaxf(mpre,  inB ? NINF : cand);
                mpost  = fmaxf(mpost, inB ? cand : NINF);
            }
            #pragma unroll
            for (int ch = 0; ch < 4; ++ch) {
                sc[ch] += (cA == (unsigned)ch ? pre : 0.0f)
                        + (cB == (unsigned)ch ? post : 0.0f);
                const float ma = (cA == (unsigned)ch) ? mpre  : NINF;
                const float mb = (cB == (unsigned)ch) ? mpost : NINF;
                mc[ch] = fmaxf(mc[ch], fmaxf(ma, mb));
            }
            pk[g][j][0] = pack2(v[0], v[1]);
            pk[g][j][1] = pack2(v[2], v[3]);
            asm volatile("" : "+v"(pk[g][j][0]), "+v"(pk[g][j][1]));
        }

        #pragma unroll
        for (int off = 32; off; off >>= 1) {
            #pragma unroll
            for (int ch = 0; ch < 4; ++ch) {
                sc[ch] += __shfl_xor(sc[ch], off);
                mc[ch]  = fmaxf(mc[ch], __shfl_xor(mc[ch], off));
            }
        }
        if (lane == 0) {
            #pragma unroll
            for (int ch = 0; ch < 4; ++ch) {
                const int   c    = 4 * gidx + ch;
                const float mean = sc[ch] * inv_div;
                p_s[c]       = mean;
                p_s[256 + c] = mean * bscale;
                p_s[512 + c] = mc[ch];
            }
        }
    }
    __syncthreads();

    // ================= MLP (R12-proven) =================
    {
        const int q = tid >> 6, s = tid & 63;
        const float* w1r = w1  + s * P3C + q * 48;
        const float* pp  = p_s + q * 48;
        float acc = 0.0f;
        #pragma unroll 8
        for (int j = 0; j < 48; ++j) acc = fmaf(pp[j], w1r[j], acc);
        part_s[q * SEH + s] = acc;
    }
    __syncthreads();
    if (tid < SEH) {
        float h = b1[tid];
        #pragma unroll
        for (int q = 0; q < NW; ++q) h += part_s[q * SEH + tid];
        hid_s[tid] = fmaxf(h, 0.0f);
    }
    __syncthreads();
    if (tid < 512) {
        float a = b2[tid];
        const float* w2r = w2 + (size_t)tid * SEH;
        #pragma unroll 8
        for (int ss = 0; ss < SEH; ++ss) a = fmaf(hid_s[ss], w2r[ss], a);
        if (tid < 256) g_s[tid]        = 1.0f / (1.0f + __expf(-a));
        else           be_s[tid - 256] = a;
    }
    __syncthreads();

    // ================= apply (zero reads of x) =================
    f32x4* o4 = (f32x4*)(out + (size_t)b * SLICE);
    #pragma unroll
    for (int g = 0; g < 4; ++g) {
        const int gidx  = 4 * wv + g;
        const int qbase = gidx * GQ;
        const int cbase = 4 * gidx;
        #pragma unroll
        for (int j = 0; j < 6; ++j) {
            if (j == 5 && lane >= 41) continue;
            const int      qi  = lane + 64 * j;
            const unsigned e0  = 4u * (unsigned)qi;
            const unsigned cA  = e0 / 361u;
            const unsigned cB  = (e0 + 3u) / 361u;
            const unsigned bnd  = cB * 361u;
            const unsigned bndA = cA * 361u;

            const float gA = g_s[cbase + cA],  gB = g_s[cbase + cB];
            const float bA = be_s[cbase + cA], bB = be_s[cbase + cB];

            const f16x2 h0 = __builtin_bit_cast(f16x2, pk[g][j][0]);
            const f16x2 h1 = __builtin_bit_cast(f16x2, pk[g][j][1]);
            const float vv[4] = {(float)h0[0], (float)h0[1],
                                 (float)h1[0], (float)h1[1]};
            f32x4 r;
            #pragma unroll
            for (int q = 0; q < 4; ++q) {
                const unsigned e   = e0 + q;
                const bool     inB = (e >= bnd);
                const unsigned hw  = e - (inB ? bnd : bndA);
                r[q] = fmaf(inB ? gB : gA, vv[q], inB ? bB : bA) * m_s[hw];
            }
            __builtin_nontemporal_store(r, &o4[qbase + qi]);
        }
    }
}

extern "C" void kernel_launch(void* const* d_in, const int* in_sizes, int n_in,
                              void* d_out, int out_size, void* d_ws, size_t ws_size,
                              hipStream_t stream) {
    const float* x     = (const float*)d_in[0];
    const float* mask  = (const float*)d_in[1];
    const float* msum  = (const float*)d_in[2];
    const float* msqrt = (const float*)d_in[3];
    const float* w1    = (const float*)d_in[4];
    const float* b1    = (const float*)d_in[5];
    const float* w2    = (const float*)d_in[6];
    const float* b2    = (const float*)d_in[7];
    float* out = (float*)d_out;

    k_se_fused<<<BB, 1024, 0, stream>>>(x, mask, msum, msqrt, w1, b1, w2, b2, out);
}